// Round 8
// baseline (17518.320 us; speedup 1.0000x reference)
//
#include <hip/hip_runtime.h>
#include <stdint.h>

#define B_ 64
#define T_ 1024
#define I_ 128
#define H_ 512
#define O_ 64
#define R16 16

typedef __attribute__((ext_vector_type(8))) short bf16x8;
typedef __attribute__((ext_vector_type(4))) float f32x4;
typedef unsigned short u16;
typedef unsigned long long u64;

struct Q2 { u64 a, b; };

__device__ __forceinline__ u16 f2bf(float f) {
  unsigned int u = __builtin_bit_cast(unsigned int, f);
  u += 0x7FFFu + ((u >> 16) & 1u);
  return (u16)(u >> 16);
}
__device__ __forceinline__ float bf2f(u16 h) {
  unsigned int u = ((unsigned int)h) << 16;
  return __builtin_bit_cast(float, u);
}
__device__ __forceinline__ u64 aload(const u64* p) {
  return __hip_atomic_load(p, __ATOMIC_RELAXED, __HIP_MEMORY_SCOPE_AGENT);
}
__device__ __forceinline__ void astore(u64* p, u64 v) {
  __hip_atomic_store(p, v, __ATOMIC_RELAXED, __HIP_MEMORY_SCOPE_AGENT);
}

// ---------- fp32 -> (hi, lo) bf16 split ----------
__global__ void split_kernel(const float* __restrict__ src,
                             u16* __restrict__ hi, u16* __restrict__ lo, int n) {
  int i = blockIdx.x * 256 + threadIdx.x;
  if (i >= n) return;
  float f = src[i];
  u16 h = f2bf(f);
  hi[i] = h;
  lo[i] = f2bf(f - bf2f(h));
}

// x [B][T][I] fp32 -> xhi/xlo [T*B][I] (row r = t*B + b)
__global__ void xsplit_kernel(const float* __restrict__ x,
                              u16* __restrict__ hi, u16* __restrict__ lo) {
  int idx = blockIdx.x * 256 + threadIdx.x;  // over T*B*I
  int i = idx & (I_ - 1);
  int b = (idx >> 7) & (B_ - 1);
  int t = idx >> 13;
  float f = x[(((size_t)b << 10) | t) * I_ + i];
  u16 h = f2bf(f);
  hi[idx] = h;
  lo[idx] = f2bf(f - bf2f(h));
}

// ring init: slot 0 <- h0 (split), slots 1..15 <- canary 0x7F80
__global__ void h0ring_kernel(const float* __restrict__ h0l,
                              u16* __restrict__ hxh, u16* __restrict__ hxl) {
  int idx = blockIdx.x * 256 + threadIdx.x;  // over R16*B*H
  int slot = idx >> 15;                      // B*H = 32768
  if (slot == 0) {
    float f = h0l[idx];
    u16 h = f2bf(f);
    hxh[idx] = h;
    hxl[idx] = f2bf(f - bf2f(h));
  } else {
    hxh[idx] = 0x7F80u;
    hxl[idx] = 0x7F80u;
  }
}

// debug sentinel
__global__ void sentinel_kernel(float* __restrict__ out, float v, int n) {
  int i = blockIdx.x * 256 + threadIdx.x;
  if (i < n) out[i] = v;
}

// ---------- projection GEMM (validated) ----------
template <int K, bool ALO>
__global__ __launch_bounds__(256) void proj_gemm(
    const u16* __restrict__ Ahi, const u16* __restrict__ Alo,
    const u16* __restrict__ Whi, const u16* __restrict__ Wlo,
    const float* __restrict__ bih, const float* __restrict__ bhh,
    float* __restrict__ xp) {
  __shared__ u16 lhs[2][128 * 72];
  const int tid = threadIdx.x;
  const int w = tid >> 6, l = tid & 63;
  const int r15 = l & 15, g4 = l >> 4;
  const int Mbase = blockIdx.x * 128;
  const int Nbase = blockIdx.y * 128;
  f32x4 acc[2][8];
#pragma unroll
  for (int bt = 0; bt < 2; ++bt)
#pragma unroll
    for (int ct = 0; ct < 8; ++ct) acc[bt][ct] = (f32x4){0.f, 0.f, 0.f, 0.f};

  for (int kc = 0; kc < K; kc += 64) {
    __syncthreads();
#pragma unroll
    for (int i = 0; i < 4; ++i) {
      int e = i * 256 + tid;
      int c = e >> 3, kg = (e & 7) * 8;
      *(uint4*)&lhs[0][c * 72 + kg] =
          *(const uint4*)(Whi + (size_t)(Nbase + c) * K + kc + kg);
      *(uint4*)&lhs[1][c * 72 + kg] =
          *(const uint4*)(Wlo + (size_t)(Nbase + c) * K + kc + kg);
    }
    __syncthreads();
#pragma unroll
    for (int kt = 0; kt < 2; ++kt) {
      bf16x8 ah[2], al[2];
#pragma unroll
      for (int bt = 0; bt < 2; ++bt) {
        int row = Mbase + w * 32 + bt * 16 + r15;
        int koff = kc + kt * 32 + g4 * 8;
        ah[bt] = *(const bf16x8*)(Ahi + (size_t)row * K + koff);
        if (ALO) al[bt] = *(const bf16x8*)(Alo + (size_t)row * K + koff);
      }
#pragma unroll
      for (int ct = 0; ct < 8; ++ct) {
        int lo_off = (ct * 16 + r15) * 72 + kt * 32 + g4 * 8;
        bf16x8 bh = *(const bf16x8*)&lhs[0][lo_off];
        bf16x8 bl = *(const bf16x8*)&lhs[1][lo_off];
#pragma unroll
        for (int bt = 0; bt < 2; ++bt) {
          acc[bt][ct] = __builtin_amdgcn_mfma_f32_16x16x32_bf16(ah[bt], bh, acc[bt][ct], 0, 0, 0);
          acc[bt][ct] = __builtin_amdgcn_mfma_f32_16x16x32_bf16(ah[bt], bl, acc[bt][ct], 0, 0, 0);
          if (ALO)
            acc[bt][ct] = __builtin_amdgcn_mfma_f32_16x16x32_bf16(al[bt], bh, acc[bt][ct], 0, 0, 0);
        }
      }
    }
  }
#pragma unroll
  for (int ct = 0; ct < 8; ++ct) {
    int col = Nbase + ct * 16 + r15;
    float bc = bih[col] + bhh[col];
#pragma unroll
    for (int bt = 0; bt < 2; ++bt) {
#pragma unroll
      for (int j = 0; j < 4; ++j) {
        int row = Mbase + w * 32 + bt * 16 + g4 * 4 + j;
        xp[(size_t)row * H_ + col] = acc[bt][ct][j] + bc;
      }
    }
  }
}

// ---------- recurrent scan: 32 WGs x 2 waves; TWO interleaved chains ----------
// WG bx: pair = bx>>4 (bgA = 2*pair, bgB = 2*pair+1), sub = bx&15.
// Wave w: j0 = (sub*2+w)*16 (same j-slice for both chains; W shared).
// Pipeline per superstep t: [spinA | issueB | stageA bar computeA |
//                            spinB | issueA(t+1) | stageB bar computeB]
// -> each chain's MALL RTT hides under the other chain's compute phase.
// Protocol identical to validated r5/r7: canary 0x7F80, scrub slot t+9,
// relaxed agent u64 atomics only; skew <= ~2 steps << 16-slot ring.
// LDS: [0,32K) bufA ; [32K,64K) bufB ; [64K,128K) per-wave W (swizzled).
#define ISSUE(S, bb, slot)                                                   \
  do {                                                                       \
    const u64* gh_ = (const u64*)(hxh + ((size_t)(slot)*B_ + (bb) + sr) * H_); \
    const u64* gl_ = (const u64*)(hxl + ((size_t)(slot)*B_ + (bb) + sr) * H_); \
    _Pragma("unroll") for (int i = 0; i < 8; ++i) {                          \
      int u_ = sc * 2 + i * 16;                                              \
      vh##S[2 * i] = aload(gh_ + u_);                                        \
      vh##S[2 * i + 1] = aload(gh_ + u_ + 1);                                \
      vl##S[2 * i] = aload(gl_ + u_);                                        \
      vl##S[2 * i + 1] = aload(gl_ + u_ + 1);                                \
    }                                                                        \
  } while (0)

#define SPIN(S, bb, slot)                                                    \
  do {                                                                       \
    for (;;) {                                                               \
      bool ok_ = true;                                                       \
      _Pragma("unroll") for (int i = 0; i < 16; ++i) ok_ =                   \
          ok_ && ((vh##S[i] >> 48) != 0x7F80ull) &&                          \
          ((vl##S[i] >> 48) != 0x7F80ull);                                   \
      if (ok_) break;                                                        \
      __builtin_amdgcn_s_sleep(1);                                           \
      ISSUE(S, bb, slot);                                                    \
    }                                                                        \
  } while (0)

#define STAGE(S, bufoff)                                                     \
  do {                                                                       \
    char* sb_ = lds + (bufoff);                                              \
    _Pragma("unroll") for (int i = 0; i < 8; ++i) {                          \
      int kb_ = (sc * 16 + i * 128) ^ sxr;                                   \
      *(uint4*)(sb_ + sr * 1024 + kb_) =                                     \
          __builtin_bit_cast(uint4, Q2{vh##S[2 * i], vh##S[2 * i + 1]});     \
      *(uint4*)(sb_ + 16384 + sr * 1024 + kb_) =                             \
          __builtin_bit_cast(uint4, Q2{vl##S[2 * i], vl##S[2 * i + 1]});     \
    }                                                                        \
  } while (0)

#define COMPUTE(bufoff, bb, xpv, xpp, t)                                     \
  do {                                                                       \
    char* cb_ = lds + (bufoff);                                              \
    f32x4 a0_ = (xpv), a1_ = {0.f, 0.f, 0.f, 0.f}, a2_ = a1_, a3_ = a1_;     \
    _Pragma("unroll") for (int kt = 0; kt < 16; ++kt) {                      \
      int kb_ = (kt * 64 + g4 * 16) ^ rxr;                                   \
      bf16x8 hv_ = *(const bf16x8*)(cb_ + rdoff + kb_);                      \
      bf16x8 lv_ = *(const bf16x8*)(cb_ + 16384 + rdoff + kb_);              \
      bf16x8 wv_ = *(const bf16x8*)(lds + wbase + rdoff + kb_);              \
      bf16x8 wl_ = *(const bf16x8*)(lds + wbase + rdoff + kb_ + 16384);      \
      f32x4* ac_ = (kt & 3) == 0   ? &a0_                                    \
                   : (kt & 3) == 1 ? &a1_                                    \
                   : (kt & 3) == 2 ? &a2_                                    \
                                   : &a3_;                                   \
      *ac_ = __builtin_amdgcn_mfma_f32_16x16x32_bf16(wv_, hv_, *ac_, 0, 0, 0); \
      *ac_ = __builtin_amdgcn_mfma_f32_16x16x32_bf16(wl_, hv_, *ac_, 0, 0, 0); \
      *ac_ = __builtin_amdgcn_mfma_f32_16x16x32_bf16(wv_, lv_, *ac_, 0, 0, 0); \
    }                                                                        \
    f32x4 s_ = (a0_ + a1_) + (a2_ + a3_);                                    \
    float v_[4];                                                             \
    _Pragma("unroll") for (int j = 0; j < 4; ++j) {                          \
      float e_ = __expf(2.0f * s_[j]);                                       \
      v_[j] = 1.0f - 2.0f * __builtin_amdgcn_rcpf(e_ + 1.0f);                \
    }                                                                        \
    u64 hip_ = 0, lop_ = 0;                                                  \
    _Pragma("unroll") for (int j = 0; j < 4; ++j) {                          \
      u16 hh_ = f2bf(v_[j]);                                                 \
      u16 ll_ = f2bf(v_[j] - bf2f(hh_));                                     \
      hip_ |= (u64)hh_ << (16 * j);                                          \
      lop_ |= (u64)ll_ << (16 * j);                                          \
    }                                                                        \
    if ((t) < T_ - 1) {                                                      \
      size_t so_ =                                                           \
          ((size_t)(((t) + 1) & 15) * B_ + (bb) + r15) * (size_t)H_ + j0 + g4 * 4; \
      astore((u64*)hxh + (so_ >> 2), hip_);                                  \
      astore((u64*)hxl + (so_ >> 2), lop_);                                  \
      size_t ss_ =                                                           \
          ((size_t)(((t) + 9) & 15) * B_ + (bb) + r15) * (size_t)H_ + j0 + g4 * 4; \
      astore((u64*)hxh + (ss_ >> 2), 0x7F807F807F807F80ull);                 \
      astore((u64*)hxl + (ss_ >> 2), 0x7F807F807F807F80ull);                 \
    }                                                                        \
    *(u64*)(yhi + ((size_t)(t)*B_ + (bb) + r15) * H_ + j0 + g4 * 4) = hip_;  \
    if ((t) == T_ - 1) {                                                     \
      f32x4 hv4_ = {v_[0], v_[1], v_[2], v_[3]};                             \
      *(f32x4*)(hn_out + (size_t)((bb) + r15) * H_ + j0 + g4 * 4) = hv4_;    \
    } else {                                                                 \
      (xpv) = *(const f32x4*)((xpp) + (size_t)((t) + 1) * B_ * H_);          \
    }                                                                        \
  } while (0)

__global__ __launch_bounds__(128, 1) void scan_kernel(
    const u16* __restrict__ whh_hi, const u16* __restrict__ whh_lo,
    const float* __restrict__ xp,
    u16* __restrict__ yhi,
    u16* __restrict__ hxh, u16* __restrict__ hxl,
    float* __restrict__ hn_out) {
  __shared__ __align__(16) char lds[131072];
  const int tid = threadIdx.x;
  const int l = tid & 63, w = tid >> 6;
  const int pair = blockIdx.x >> 4, sub = blockIdx.x & 15;
  const int r15 = l & 15, g4 = l >> 4;
  const int j0 = (sub * 2 + w) * 16;
  const int bbA = pair * 32, bbB = bbA + 16;
  const int wbase = 65536 + w * 32768;

  // --- W fill (once): row-major 16x512 per plane, XOR-swizzled 16B chunks
#pragma unroll
  for (int i = 0; i < 16; ++i) {
    int row = i, cc = l;
    int dst = wbase + row * 1024 + ((cc * 16) ^ ((row & 7) << 4));
    *(uint4*)(lds + dst) = *(const uint4*)(whh_hi + (size_t)(j0 + row) * H_ + cc * 8);
    *(uint4*)(lds + dst + 16384) = *(const uint4*)(whh_lo + (size_t)(j0 + row) * H_ + cc * 8);
  }
  __syncthreads();

  const int sr = tid >> 3, sc = tid & 7;
  const int sxr = (sr & 7) << 4;   // write-side XOR
  const int rxr = (r15 & 7) << 4;  // read-side XOR
  const int rdoff = r15 * 1024;

  const float* xppA = xp + (size_t)(bbA + r15) * H_ + j0 + g4 * 4;
  const float* xppB = xp + (size_t)(bbB + r15) * H_ + j0 + g4 * 4;
  f32x4 xpvA = *(const f32x4*)xppA;
  f32x4 xpvB = *(const f32x4*)xppB;

  u64 vhA[16], vlA[16], vhB[16], vlB[16];
  ISSUE(A, bbA, 0);  // prefetch chain A, t=0 (ring slot 0 pre-filled with h0)

  for (int t = 0; t < T_; ++t) {
    const int slot = t & 15;
    SPIN(A, bbA, slot);
    ISSUE(B, bbB, slot);  // B's RTT hides under A's stage+compute
    __builtin_amdgcn_sched_barrier(0);
    STAGE(A, 0);
    __syncthreads();
    COMPUTE(0, bbA, xpvA, xppA, t);
    SPIN(B, bbB, slot);
    if (t < T_ - 1) {
      ISSUE(A, bbA, (t + 1) & 15);  // A(t+1)'s RTT hides under B's compute
      __builtin_amdgcn_sched_barrier(0);
    }
    STAGE(B, 32768);
    __syncthreads();
    COMPUTE(32768, bbB, xpvB, xppB, t);
  }
}

// ---------- final FC + sigmoid ----------
__global__ __launch_bounds__(64) void fc_kernel(const float* __restrict__ hn2,
                                                const float* __restrict__ wfc,
                                                const float* __restrict__ bfc,
                                                float* __restrict__ out) {
  int b = blockIdx.x, o = threadIdx.x;
  __shared__ float hs[H_];
  for (int i = o; i < H_; i += 64) hs[i] = hn2[(size_t)b * H_ + i];
  __syncthreads();
  float acc = bfc[o];
#pragma unroll 4
  for (int k = 0; k < H_; k += 4) {
    float4 wv = *(const float4*)(wfc + (size_t)o * H_ + k);
    acc += hs[k] * wv.x + hs[k + 1] * wv.y + hs[k + 2] * wv.z + hs[k + 3] * wv.w;
  }
  out[b * O_ + o] = 1.f / (1.f + expf(-acc));
}

extern "C" void kernel_launch(void* const* d_in, const int* in_sizes, int n_in,
                              void* d_out, int out_size, void* d_ws, size_t ws_size,
                              hipStream_t stream) {
  (void)in_sizes; (void)n_in; (void)out_size;
  const float* x = (const float*)d_in[0];
  const float* h0 = (const float*)d_in[1];
  const float* w_ih[3] = {(const float*)d_in[2], (const float*)d_in[6], (const float*)d_in[10]};
  const float* w_hh[3] = {(const float*)d_in[3], (const float*)d_in[7], (const float*)d_in[11]};
  const float* b_ih[3] = {(const float*)d_in[4], (const float*)d_in[8], (const float*)d_in[12]};
  const float* b_hh[3] = {(const float*)d_in[5], (const float*)d_in[9], (const float*)d_in[13]};
  const float* w_fc = (const float*)d_in[14];
  const float* b_fc = (const float*)d_in[15];
  float* out = (float*)d_out;
  float* hn = out + B_ * O_;

  char* p = (char*)d_ws;
  auto carve = [&](size_t bytes) {
    char* r = p;
    p += (bytes + 255) & ~(size_t)255;
    return r;
  };
  float* xp = (float*)carve((size_t)T_ * B_ * H_ * 4);   // 128 MiB
  u16* yhi = (u16*)carve((size_t)T_ * B_ * H_ * 2);      // 64 MiB
  u16* hxh = (u16*)carve((size_t)R16 * B_ * H_ * 2);     // 1 MiB
  u16* hxl = (u16*)carve((size_t)R16 * B_ * H_ * 2);     // 1 MiB
  u16 *whhh[3], *whhl[3], *wihh[3], *wihl[3];
  for (int l = 0; l < 3; ++l) {
    whhh[l] = (u16*)carve((size_t)H_ * H_ * 2);
    whhl[l] = (u16*)carve((size_t)H_ * H_ * 2);
    int kin = (l == 0) ? I_ : H_;
    wihh[l] = (u16*)carve((size_t)H_ * kin * 2);
    wihl[l] = (u16*)carve((size_t)H_ * kin * 2);
  }
  size_t required = (size_t)(p - (char*)d_ws);
  if (required > ws_size) {
    int n = B_ * O_ + 3 * B_ * H_;
    sentinel_kernel<<<(n + 255) / 256, 256, 0, stream>>>(out, (float)(ws_size >> 20), n);
    return;
  }
  // x-split aliases the yhi region (dead before scan-0 writes yhi)
  u16* xhi = yhi;
  u16* xlo = yhi + (size_t)T_ * B_ * I_;

  for (int l = 0; l < 3; ++l) {
    split_kernel<<<H_ * H_ / 256, 256, 0, stream>>>(w_hh[l], whhh[l], whhl[l], H_ * H_);
    int kin = (l == 0) ? I_ : H_;
    split_kernel<<<H_ * kin / 256, 256, 0, stream>>>(w_ih[l], wihh[l], wihl[l], H_ * kin);
  }
  xsplit_kernel<<<T_ * B_ * I_ / 256, 256, 0, stream>>>(x, xhi, xlo);

  for (int l = 0; l < 3; ++l) {
    h0ring_kernel<<<R16 * B_ * H_ / 256, 256, 0, stream>>>(h0 + (size_t)l * B_ * H_, hxh, hxl);
    if (l == 0)
      proj_gemm<I_, true><<<dim3(T_ * B_ / 128, H_ / 128), 256, 0, stream>>>(
          xhi, xlo, wihh[0], wihl[0], b_ih[0], b_hh[0], xp);
    else
      proj_gemm<H_, false><<<dim3(T_ * B_ / 128, H_ / 128), 256, 0, stream>>>(
          yhi, yhi, wihh[l], wihl[l], b_ih[l], b_hh[l], xp);
    scan_kernel<<<32, 128, 0, stream>>>(whhh[l], whhl[l], xp, yhi, hxh, hxl,
                                        hn + (size_t)l * B_ * H_);
  }
  fc_kernel<<<B_, O_, 0, stream>>>(hn + 2 * (size_t)B_ * H_, w_fc, b_fc, out);
}

// Round 9
// 11136.965 us; speedup vs baseline: 1.5730x; 1.5730x over previous
//
#include <hip/hip_runtime.h>
#include <stdint.h>

#define B_ 64
#define T_ 1024
#define I_ 128
#define H_ 512
#define O_ 64
#define R16 16
#define TBH ((size_t)T_ * B_ * H_)

typedef __attribute__((ext_vector_type(8))) short bf16x8;
typedef __attribute__((ext_vector_type(4))) float f32x4;
typedef unsigned short u16;
typedef unsigned long long u64;

struct Q2 { u64 a, b; };

__device__ __forceinline__ u16 f2bf(float f) {
  unsigned int u = __builtin_bit_cast(unsigned int, f);
  u += 0x7FFFu + ((u >> 16) & 1u);
  return (u16)(u >> 16);
}
__device__ __forceinline__ float bf2f(u16 h) {
  unsigned int u = ((unsigned int)h) << 16;
  return __builtin_bit_cast(float, u);
}
__device__ __forceinline__ u64 aload(const u64* p) {
  return __hip_atomic_load(p, __ATOMIC_RELAXED, __HIP_MEMORY_SCOPE_AGENT);
}
__device__ __forceinline__ void astore(u64* p, u64 v) {
  __hip_atomic_store(p, v, __ATOMIC_RELAXED, __HIP_MEMORY_SCOPE_AGENT);
}

// ---------- fp32 -> (hi, lo) bf16 split ----------
__global__ void split_kernel(const float* __restrict__ src,
                             u16* __restrict__ hi, u16* __restrict__ lo, int n) {
  int i = blockIdx.x * 256 + threadIdx.x;
  if (i >= n) return;
  float f = src[i];
  u16 h = f2bf(f);
  hi[i] = h;
  lo[i] = f2bf(f - bf2f(h));
}

// x [B][T][I] fp32 -> xhi/xlo [T*B][I] (row r = t*B + b)
__global__ void xsplit_kernel(const float* __restrict__ x,
                              u16* __restrict__ hi, u16* __restrict__ lo) {
  int idx = blockIdx.x * 256 + threadIdx.x;  // over T*B*I
  int i = idx & (I_ - 1);
  int b = (idx >> 7) & (B_ - 1);
  int t = idx >> 13;
  float f = x[(((size_t)b << 10) | t) * I_ + i];
  u16 h = f2bf(f);
  hi[idx] = h;
  lo[idx] = f2bf(f - bf2f(h));
}

// ring init: slot 0 <- h0 (split), slots 1..15 <- canary 0x7F80
__global__ void h0ring_kernel(const float* __restrict__ h0l,
                              u16* __restrict__ hxh, u16* __restrict__ hxl) {
  int idx = blockIdx.x * 256 + threadIdx.x;  // over R16*B*H
  int slot = idx >> 15;                      // B*H = 32768
  if (slot == 0) {
    float f = h0l[idx];
    u16 h = f2bf(f);
    hxh[idx] = h;
    hxl[idx] = f2bf(f - bf2f(h));
  } else {
    hxh[idx] = 0x7F80u;
    hxl[idx] = 0x7F80u;
  }
}

// canary-fill y buffers (u32 granularity)
__global__ void ycan_kernel(unsigned int* __restrict__ p) {
  size_t i = (size_t)blockIdx.x * 256 + threadIdx.x;
  p[i] = 0x7F807F80u;
}

// bsum[j] = bih[j] + bhh[j]
__global__ void bsum_kernel(const float* __restrict__ bih,
                            const float* __restrict__ bhh, float* __restrict__ out) {
  int i = blockIdx.x * 256 + threadIdx.x;
  if (i < H_) out[i] = bih[i] + bhh[i];
}

// debug sentinel
__global__ void sentinel_kernel(float* __restrict__ out, float v, int n) {
  int i = blockIdx.x * 256 + threadIdx.x;
  if (i < n) out[i] = v;
}

// ---------- fused 3-layer pipelined RNN ----------
// grid = 192 WGs x 128 thr (2 waves). layer = bx>>6; sub = bx&63; bg = sub>>4 (16
// batch rows); jp = sub&15; wave w -> j0 = (jp*2+w)*16.
// Co-residency: 192 WGs <= 256 CUs at <=128KB LDS -> all resident (in-order
// dispatch places every WG; layers form a DAG 0->1->2, spins use s_sleep).
// Per wave LDS (w*65536): [0)WhhHi [16K)WhhLo [32K)WihHi [48K)WihLo, each
// [16 rows][1024B] with 16B-chunk XOR swizzle ((row&7)<<4).
// h via per-layer canary ring (validated r4-r7 protocol: relaxed agent u64
// atomics, canary 0x7F80, scrub t+9). y0/y1: T-indexed canary buffers
// (written once per location -> no scrub). Layer0 consumes pre-split x (always
// ready, plain loads). z = bsum + Wih*in + Whh*h; h' = tanh(z).
// Numerics identical to the validated per-layer path (same MFMA terms).
__global__ __launch_bounds__(128, 1) void rnn3_kernel(
    const u16* __restrict__ whh_hi, const u16* __restrict__ whh_lo,
    const u16* __restrict__ wih_hi, const u16* __restrict__ wih_lo,
    const u16* __restrict__ xhi, const u16* __restrict__ xlo,
    const float* __restrict__ bsum_all,
    u16* __restrict__ y,
    u16* __restrict__ hxh, u16* __restrict__ hxl,
    float* __restrict__ hn) {
  __shared__ __align__(16) char lds[131072];
  const int tid = threadIdx.x;
  const int l = tid & 63, w = tid >> 6;
  const int layer = blockIdx.x >> 6, sub = blockIdx.x & 63;
  const int bg = sub >> 4, jp = sub & 15;
  const int r15 = l & 15, g4 = l >> 4;
  const int j0 = (jp * 2 + w) * 16, bb = bg * 16;
  char* wb = lds + w * 65536;

  // --- W fills (own-wave region; no barrier needed: only this wave reads it)
  const u16* whhH = whh_hi + (size_t)layer * 262144;
  const u16* whhL = whh_lo + (size_t)layer * 262144;
#pragma unroll
  for (int i = 0; i < 16; ++i) {
    int dst = i * 1024 + ((l * 16) ^ ((i & 7) << 4));
    *(uint4*)(wb + dst) = *(const uint4*)(whhH + (size_t)(j0 + i) * 512 + l * 8);
    *(uint4*)(wb + 16384 + dst) = *(const uint4*)(whhL + (size_t)(j0 + i) * 512 + l * 8);
  }
  const u16* wihH = wih_hi + (size_t)layer * 262144;
  const u16* wihL = wih_lo + (size_t)layer * 262144;
  if (layer == 0) {
#pragma unroll
    for (int i = 0; i < 4; ++i) {
      int e = i * 64 + l, row = e >> 4, c = e & 15;
      int dst = row * 1024 + ((c * 16) ^ ((row & 7) << 4));
      *(uint4*)(wb + 32768 + dst) = *(const uint4*)(wihH + (size_t)(j0 + row) * 128 + c * 8);
      *(uint4*)(wb + 49152 + dst) = *(const uint4*)(wihL + (size_t)(j0 + row) * 128 + c * 8);
    }
  } else {
#pragma unroll
    for (int i = 0; i < 16; ++i) {
      int dst = i * 1024 + ((l * 16) ^ ((i & 7) << 4));
      *(uint4*)(wb + 32768 + dst) = *(const uint4*)(wihH + (size_t)(j0 + i) * 512 + l * 8);
      *(uint4*)(wb + 49152 + dst) = *(const uint4*)(wihL + (size_t)(j0 + i) * 512 + l * 8);
    }
  }
  const float* bs = bsum_all + layer * H_ + j0 + g4 * 4;
  const float b0 = bs[0], b1 = bs[1], b2 = bs[2], b3 = bs[3];

  u16* rhH = hxh + (size_t)layer * (R16 * B_ * H_);
  u16* rhL = hxl + (size_t)layer * (R16 * B_ * H_);
  const u16* yin = (layer > 0) ? (y + (size_t)(layer - 1) * TBH) : y;
  u16* yout = (layer < 2) ? (y + (size_t)layer * TBH) : y;
  float* hno = hn + (size_t)layer * B_ * H_;
  const int rxr = (r15 & 7) << 4;
  const int rdoff = r15 * 1024;

  for (int t = 0; t < T_; ++t) {
    const int slot = t & 15;
    const u64* gh = (const u64*)(rhH + ((size_t)slot * B_ + bb + r15) * H_) + g4 * 2;
    const u64* gl = (const u64*)(rhL + ((size_t)slot * B_ + bb + r15) * H_) + g4 * 2;
    const u64* gy = (const u64*)(yin + ((size_t)t * B_ + bb + r15) * H_) + g4 * 2;

    uint4 fx[4][2];
    if (layer == 0) {
      const u16* xr = xhi + ((size_t)t * B_ + bb + r15) * I_ + g4 * 8;
      const u16* xq = xlo + ((size_t)t * B_ + bb + r15) * I_ + g4 * 8;
#pragma unroll
      for (int kt = 0; kt < 4; ++kt) {
        fx[kt][0] = *(const uint4*)(xr + kt * 32);
        fx[kt][1] = *(const uint4*)(xq + kt * 32);
      }
    }

    u64 fh[32], fl[32], fy[32];
    for (;;) {
#pragma unroll
      for (int kt = 0; kt < 16; ++kt) {
        fh[2 * kt] = aload(gh + kt * 8);
        fh[2 * kt + 1] = aload(gh + kt * 8 + 1);
        fl[2 * kt] = aload(gl + kt * 8);
        fl[2 * kt + 1] = aload(gl + kt * 8 + 1);
      }
      if (layer > 0) {
#pragma unroll
        for (int kt = 0; kt < 16; ++kt) {
          fy[2 * kt] = aload(gy + kt * 8);
          fy[2 * kt + 1] = aload(gy + kt * 8 + 1);
        }
      }
      bool ok = true;
#pragma unroll
      for (int i = 0; i < 32; ++i)
        ok = ok && ((fh[i] >> 48) != 0x7F80ull) && ((fl[i] >> 48) != 0x7F80ull);
      if (layer > 0) {
#pragma unroll
        for (int i = 0; i < 32; ++i) ok = ok && ((fy[i] >> 48) != 0x7F80ull);
      }
      if (ok) break;
      __builtin_amdgcn_s_sleep(1);
    }

    f32x4 a0 = {b0, b1, b2, b3};
    f32x4 a1 = {0.f, 0.f, 0.f, 0.f}, a2 = a1, a3 = a1;
#pragma unroll
    for (int kt = 0; kt < 16; ++kt) {
      int kb = (kt * 64 + g4 * 16) ^ rxr;
      bf16x8 whv = *(const bf16x8*)(wb + rdoff + kb);
      bf16x8 wlv = *(const bf16x8*)(wb + 16384 + rdoff + kb);
      bf16x8 hv = __builtin_bit_cast(bf16x8, Q2{fh[2 * kt], fh[2 * kt + 1]});
      bf16x8 lv = __builtin_bit_cast(bf16x8, Q2{fl[2 * kt], fl[2 * kt + 1]});
      f32x4* ac = (kt & 3) == 0 ? &a0 : (kt & 3) == 1 ? &a1 : (kt & 3) == 2 ? &a2 : &a3;
      *ac = __builtin_amdgcn_mfma_f32_16x16x32_bf16(whv, hv, *ac, 0, 0, 0);
      *ac = __builtin_amdgcn_mfma_f32_16x16x32_bf16(wlv, hv, *ac, 0, 0, 0);
      *ac = __builtin_amdgcn_mfma_f32_16x16x32_bf16(whv, lv, *ac, 0, 0, 0);
      if (layer > 0) {
        bf16x8 wiv = *(const bf16x8*)(wb + 32768 + rdoff + kb);
        bf16x8 wjv = *(const bf16x8*)(wb + 49152 + rdoff + kb);
        bf16x8 yv = __builtin_bit_cast(bf16x8, Q2{fy[2 * kt], fy[2 * kt + 1]});
        int d = (kt + 2) & 3;
        f32x4* ad = d == 0 ? &a0 : d == 1 ? &a1 : d == 2 ? &a2 : &a3;
        *ad = __builtin_amdgcn_mfma_f32_16x16x32_bf16(wiv, yv, *ad, 0, 0, 0);
        *ad = __builtin_amdgcn_mfma_f32_16x16x32_bf16(wjv, yv, *ad, 0, 0, 0);
      }
    }
    if (layer == 0) {
#pragma unroll
      for (int kt = 0; kt < 4; ++kt) {
        int kb = (kt * 64 + g4 * 16) ^ rxr;
        bf16x8 wiv = *(const bf16x8*)(wb + 32768 + rdoff + kb);
        bf16x8 wjv = *(const bf16x8*)(wb + 49152 + rdoff + kb);
        bf16x8 xv = __builtin_bit_cast(bf16x8, fx[kt][0]);
        bf16x8 xq = __builtin_bit_cast(bf16x8, fx[kt][1]);
        a0 = __builtin_amdgcn_mfma_f32_16x16x32_bf16(wiv, xv, a0, 0, 0, 0);
        a1 = __builtin_amdgcn_mfma_f32_16x16x32_bf16(wjv, xv, a1, 0, 0, 0);
        a2 = __builtin_amdgcn_mfma_f32_16x16x32_bf16(wiv, xq, a2, 0, 0, 0);
      }
    }
    f32x4 s = (a0 + a1) + (a2 + a3);
    float v[4];
#pragma unroll
    for (int j = 0; j < 4; ++j) {
      float e = __expf(2.0f * s[j]);
      v[j] = 1.0f - 2.0f * __builtin_amdgcn_rcpf(e + 1.0f);
    }
    u64 hip = 0, lop = 0;
#pragma unroll
    for (int j = 0; j < 4; ++j) {
      u16 hh = f2bf(v[j]);
      u16 ll = f2bf(v[j] - bf2f(hh));
      hip |= (u64)hh << (16 * j);
      lop |= (u64)ll << (16 * j);
    }
    if (t < T_ - 1) {
      size_t so = ((size_t)((t + 1) & 15) * B_ + bb + r15) * (size_t)H_ + j0 + g4 * 4;
      astore((u64*)rhH + (so >> 2), hip);
      astore((u64*)rhL + (so >> 2), lop);
      size_t ss = ((size_t)((t + 9) & 15) * B_ + bb + r15) * (size_t)H_ + j0 + g4 * 4;
      astore((u64*)rhH + (ss >> 2), 0x7F807F807F807F80ull);
      astore((u64*)rhL + (ss >> 2), 0x7F807F807F807F80ull);
    }
    if (layer < 2) {
      size_t yo = ((size_t)t * B_ + bb + r15) * (size_t)H_ + j0 + g4 * 4;
      astore((u64*)yout + (yo >> 2), hip);
    }
    if (t == T_ - 1) {
      f32x4 hv4 = {v[0], v[1], v[2], v[3]};
      *(f32x4*)(hno + (size_t)(bb + r15) * H_ + j0 + g4 * 4) = hv4;
    }
  }
}

// ---------- final FC + sigmoid ----------
__global__ __launch_bounds__(64) void fc_kernel(const float* __restrict__ hn2,
                                                const float* __restrict__ wfc,
                                                const float* __restrict__ bfc,
                                                float* __restrict__ out) {
  int b = blockIdx.x, o = threadIdx.x;
  __shared__ float hs[H_];
  for (int i = o; i < H_; i += 64) hs[i] = hn2[(size_t)b * H_ + i];
  __syncthreads();
  float acc = bfc[o];
#pragma unroll 4
  for (int k = 0; k < H_; k += 4) {
    float4 wv = *(const float4*)(wfc + (size_t)o * H_ + k);
    acc += hs[k] * wv.x + hs[k + 1] * wv.y + hs[k + 2] * wv.z + hs[k + 3] * wv.w;
  }
  out[b * O_ + o] = 1.f / (1.f + expf(-acc));
}

extern "C" void kernel_launch(void* const* d_in, const int* in_sizes, int n_in,
                              void* d_out, int out_size, void* d_ws, size_t ws_size,
                              hipStream_t stream) {
  (void)in_sizes; (void)n_in; (void)out_size;
  const float* x = (const float*)d_in[0];
  const float* h0 = (const float*)d_in[1];
  const float* w_ih[3] = {(const float*)d_in[2], (const float*)d_in[6], (const float*)d_in[10]};
  const float* w_hh[3] = {(const float*)d_in[3], (const float*)d_in[7], (const float*)d_in[11]};
  const float* b_ih[3] = {(const float*)d_in[4], (const float*)d_in[8], (const float*)d_in[12]};
  const float* b_hh[3] = {(const float*)d_in[5], (const float*)d_in[9], (const float*)d_in[13]};
  const float* w_fc = (const float*)d_in[14];
  const float* b_fc = (const float*)d_in[15];
  float* out = (float*)d_out;
  float* hn = out + B_ * O_;

  char* p = (char*)d_ws;
  auto carve = [&](size_t bytes) {
    char* r = p;
    p += (bytes + 255) & ~(size_t)255;
    return r;
  };
  u16* y = (u16*)carve(2 * TBH * 2);                        // 128 MiB
  u16* xhi = (u16*)carve((size_t)T_ * B_ * I_ * 2);         // 16 MiB
  u16* xlo = (u16*)carve((size_t)T_ * B_ * I_ * 2);         // 16 MiB
  u16* hxh = (u16*)carve((size_t)3 * R16 * B_ * H_ * 2);    // 3 MiB
  u16* hxl = (u16*)carve((size_t)3 * R16 * B_ * H_ * 2);    // 3 MiB
  u16* whh_hi = (u16*)carve((size_t)3 * 262144 * 2);        // 1.5 MiB
  u16* whh_lo = (u16*)carve((size_t)3 * 262144 * 2);
  u16* wih_hi = (u16*)carve((size_t)3 * 262144 * 2);
  u16* wih_lo = (u16*)carve((size_t)3 * 262144 * 2);
  float* bsum = (float*)carve((size_t)3 * H_ * 4);
  size_t required = (size_t)(p - (char*)d_ws);
  if (required > ws_size) {
    int n = B_ * O_ + 3 * B_ * H_;
    sentinel_kernel<<<(n + 255) / 256, 256, 0, stream>>>(out, (float)(ws_size >> 20), n);
    return;
  }

  for (int l = 0; l < 3; ++l) {
    split_kernel<<<262144 / 256, 256, 0, stream>>>(w_hh[l], whh_hi + l * 262144,
                                                   whh_lo + l * 262144, 262144);
    int nih = (l == 0) ? H_ * I_ : H_ * H_;
    split_kernel<<<(nih + 255) / 256, 256, 0, stream>>>(w_ih[l], wih_hi + l * 262144,
                                                        wih_lo + l * 262144, nih);
    bsum_kernel<<<2, 256, 0, stream>>>(b_ih[l], b_hh[l], bsum + l * H_);
    h0ring_kernel<<<R16 * B_ * H_ / 256, 256, 0, stream>>>(
        h0 + (size_t)l * B_ * H_, hxh + (size_t)l * R16 * B_ * H_,
        hxl + (size_t)l * R16 * B_ * H_);
  }
  xsplit_kernel<<<T_ * B_ * I_ / 256, 256, 0, stream>>>(x, xhi, xlo);
  ycan_kernel<<<(unsigned)(TBH / 256), 256, 0, stream>>>((unsigned int*)y);

  rnn3_kernel<<<192, 128, 0, stream>>>(whh_hi, whh_lo, wih_hi, wih_lo, xhi, xlo,
                                       bsum, y, hxh, hxl, hn);
  fc_kernel<<<B_, O_, 0, stream>>>(hn + 2 * (size_t)B_ * H_, w_fc, b_fc, out);
}

// Round 10
// 8768.546 us; speedup vs baseline: 1.9979x; 1.2701x over previous
//
#include <hip/hip_runtime.h>
#include <stdint.h>

#define B_ 64
#define T_ 1024
#define I_ 128
#define H_ 512
#define O_ 64
#define R16 16
#define TBH ((size_t)T_ * B_ * H_)

typedef __attribute__((ext_vector_type(8))) short bf16x8;
typedef __attribute__((ext_vector_type(4))) float f32x4;
typedef unsigned short u16;
typedef unsigned long long u64;

struct Q2 { u64 a, b; };

__device__ __forceinline__ u16 f2bf(float f) {
  unsigned int u = __builtin_bit_cast(unsigned int, f);
  u += 0x7FFFu + ((u >> 16) & 1u);
  return (u16)(u >> 16);
}
__device__ __forceinline__ float bf2f(u16 h) {
  unsigned int u = ((unsigned int)h) << 16;
  return __builtin_bit_cast(float, u);
}
__device__ __forceinline__ u64 aload(const u64* p) {
  return __hip_atomic_load(p, __ATOMIC_RELAXED, __HIP_MEMORY_SCOPE_AGENT);
}
__device__ __forceinline__ void astore(u64* p, u64 v) {
  __hip_atomic_store(p, v, __ATOMIC_RELAXED, __HIP_MEMORY_SCOPE_AGENT);
}

// ---------- fp32 -> (hi, lo) bf16 split ----------
__global__ void split_kernel(const float* __restrict__ src,
                             u16* __restrict__ hi, u16* __restrict__ lo, int n) {
  int i = blockIdx.x * 256 + threadIdx.x;
  if (i >= n) return;
  float f = src[i];
  u16 h = f2bf(f);
  hi[i] = h;
  lo[i] = f2bf(f - bf2f(h));
}

// x [B][T][I] fp32 -> xhi/xlo [T*B][I] (row r = t*B + b)
__global__ void xsplit_kernel(const float* __restrict__ x,
                              u16* __restrict__ hi, u16* __restrict__ lo) {
  int idx = blockIdx.x * 256 + threadIdx.x;  // over T*B*I
  int i = idx & (I_ - 1);
  int b = (idx >> 7) & (B_ - 1);
  int t = idx >> 13;
  float f = x[(((size_t)b << 10) | t) * I_ + i];
  u16 h = f2bf(f);
  hi[idx] = h;
  lo[idx] = f2bf(f - bf2f(h));
}

// ring init: slot 0 <- h0 (split), slots 1..15 <- canary 0x7F80
__global__ void h0ring_kernel(const float* __restrict__ h0l,
                              u16* __restrict__ hxh, u16* __restrict__ hxl) {
  int idx = blockIdx.x * 256 + threadIdx.x;  // over R16*B*H
  int slot = idx >> 15;                      // B*H = 32768
  if (slot == 0) {
    float f = h0l[idx];
    u16 h = f2bf(f);
    hxh[idx] = h;
    hxl[idx] = f2bf(f - bf2f(h));
  } else {
    hxh[idx] = 0x7F80u;
    hxl[idx] = 0x7F80u;
  }
}

// canary-fill y buffers (u32 granularity)
__global__ void ycan_kernel(unsigned int* __restrict__ p) {
  size_t i = (size_t)blockIdx.x * 256 + threadIdx.x;
  p[i] = 0x7F807F80u;
}

// bsum[j] = bih[j] + bhh[j]
__global__ void bsum_kernel(const float* __restrict__ bih,
                            const float* __restrict__ bhh, float* __restrict__ out) {
  int i = blockIdx.x * 256 + threadIdx.x;
  if (i < H_) out[i] = bih[i] + bhh[i];
}

// debug sentinel
__global__ void sentinel_kernel(float* __restrict__ out, float v, int n) {
  int i = blockIdx.x * 256 + threadIdx.x;
  if (i < n) out[i] = v;
}

// ---------- fused 3-layer pipelined RNN, flag-gated single-pass exchange ------
// grid = 384 WGs x 64 thr (1 wave). layer = bx>>7; sub = bx&127; bg = sub>>5
// (16 batch rows); slice = sub&31 -> j0 = slice*16.
// Co-residency: 64KB LDS -> 2 WGs/CU; 384 <= 512 -> all resident.
// LDS (one wave): [0)WhhHi [16K)WhhLo [32K)WihHi [48K)WihLo, each [16][1024B],
// 16B-chunk XOR swizzle ((row&7)<<4).
// Exchange: per-layer canary ring (validated r4-r9: relaxed agent u64 atomics,
// canary 0x7F80, scrub t+9) + y (T-indexed, canary-init) UNCHANGED, plus a
// monotonic per-producer-wave flag (relaxed 8B store fired right after the data
// stores, NO vmcnt). Consumers gate on flags (512B/attempt), then load data
// once; the in-data canary check remains the correctness net for the rare
// flag-ahead-of-data race (bounded retry). No ordering assumptions added.
__global__ __launch_bounds__(64, 1) void rnn3_kernel(
    const u16* __restrict__ whh_hi, const u16* __restrict__ whh_lo,
    const u16* __restrict__ wih_hi, const u16* __restrict__ wih_lo,
    const u16* __restrict__ xhi, const u16* __restrict__ xlo,
    const float* __restrict__ bsum_all,
    u16* __restrict__ y,
    u16* __restrict__ hxh, u16* __restrict__ hxl,
    u64* __restrict__ flags,
    float* __restrict__ hn) {
  __shared__ __align__(16) char wb[65536];
  const int l = threadIdx.x;
  const int layer = blockIdx.x >> 7, sub = blockIdx.x & 127;
  const int bg = sub >> 5, slice = sub & 31;
  const int r15 = l & 15, g4 = l >> 4;
  const int j0 = slice * 16, bb = bg * 16;

  // --- W fills (single wave, own LDS; no barrier needed)
  const u16* whhH = whh_hi + (size_t)layer * 262144;
  const u16* whhL = whh_lo + (size_t)layer * 262144;
#pragma unroll
  for (int i = 0; i < 16; ++i) {
    int dst = i * 1024 + ((l * 16) ^ ((i & 7) << 4));
    *(uint4*)(wb + dst) = *(const uint4*)(whhH + (size_t)(j0 + i) * 512 + l * 8);
    *(uint4*)(wb + 16384 + dst) = *(const uint4*)(whhL + (size_t)(j0 + i) * 512 + l * 8);
  }
  const u16* wihH = wih_hi + (size_t)layer * 262144;
  const u16* wihL = wih_lo + (size_t)layer * 262144;
  if (layer == 0) {
#pragma unroll
    for (int i = 0; i < 4; ++i) {
      int e = i * 64 + l, row = e >> 4, c = e & 15;
      int dst = row * 1024 + ((c * 16) ^ ((row & 7) << 4));
      *(uint4*)(wb + 32768 + dst) = *(const uint4*)(wihH + (size_t)(j0 + row) * 128 + c * 8);
      *(uint4*)(wb + 49152 + dst) = *(const uint4*)(wihL + (size_t)(j0 + row) * 128 + c * 8);
    }
  } else {
#pragma unroll
    for (int i = 0; i < 16; ++i) {
      int dst = i * 1024 + ((l * 16) ^ ((i & 7) << 4));
      *(uint4*)(wb + 32768 + dst) = *(const uint4*)(wihH + (size_t)(j0 + i) * 512 + l * 8);
      *(uint4*)(wb + 49152 + dst) = *(const uint4*)(wihL + (size_t)(j0 + i) * 512 + l * 8);
    }
  }
  const float* bs = bsum_all + layer * H_ + j0 + g4 * 4;
  const float b0 = bs[0], b1 = bs[1], b2 = bs[2], b3 = bs[3];

  u16* rhH = hxh + (size_t)layer * (R16 * B_ * H_);
  u16* rhL = hxl + (size_t)layer * (R16 * B_ * H_);
  const u16* yin = (layer > 0) ? (y + (size_t)(layer - 1) * TBH) : y;
  u16* yout = (layer < 2) ? (y + (size_t)layer * TBH) : y;
  float* hno = hn + (size_t)layer * B_ * H_;
  u64* myflag = flags + ((size_t)layer * 4 + bg) * 32 + slice;
  const u64* hfl = flags + ((size_t)layer * 4 + bg) * 32;
  const u64* yfl = (layer > 0) ? flags + ((size_t)(layer - 1) * 4 + bg) * 32 : hfl;
  const int rxr = (r15 & 7) << 4;
  const int rdoff = r15 * 1024;
  // gate setup: lane<32 polls h-flag[lane] (>=t); lane>=32 polls y-flag[lane-32] (>=t+1)
  const int gs = l & 31;
  const bool gIsH = l < 32;
  const u64* gfp = gIsH ? (hfl + gs) : (yfl + gs);
  const bool gAct = gIsH ? true : (layer > 0);

  for (int t = 0; t < T_; ++t) {
    const int slot = t & 15;
    const u64* gh = (const u64*)(rhH + ((size_t)slot * B_ + bb + r15) * H_) + g4 * 2;
    const u64* gl = (const u64*)(rhL + ((size_t)slot * B_ + bb + r15) * H_) + g4 * 2;
    const u64* gy = (const u64*)(yin + ((size_t)t * B_ + bb + r15) * H_) + g4 * 2;

    uint4 fx[4][2];
    if (layer == 0) {
      const u16* xr = xhi + ((size_t)t * B_ + bb + r15) * I_ + g4 * 8;
      const u16* xq = xlo + ((size_t)t * B_ + bb + r15) * I_ + g4 * 8;
#pragma unroll
      for (int kt = 0; kt < 4; ++kt) {
        fx[kt][0] = *(const uint4*)(xr + kt * 32);
        fx[kt][1] = *(const uint4*)(xq + kt * 32);
      }
    }

    // --- flag gate (512B/attempt) ---
    if (t > 0 || layer > 0) {
      const u64 tgt = gIsH ? (u64)t : (u64)(t + 1);
      const bool act = gAct && (gIsH ? (t > 0) : true);
      for (;;) {
        int ok = 1;
        if (act) ok = (aload(gfp) >= tgt) ? 1 : 0;
        if (__all(ok)) break;
        __builtin_amdgcn_s_sleep(2);
      }
    }

    // --- single-pass data load with canary verify (retry rare) ---
    u64 fh[32], fl[32], fy[32];
    for (;;) {
#pragma unroll
      for (int kt = 0; kt < 16; ++kt) {
        fh[2 * kt] = aload(gh + kt * 8);
        fh[2 * kt + 1] = aload(gh + kt * 8 + 1);
        fl[2 * kt] = aload(gl + kt * 8);
        fl[2 * kt + 1] = aload(gl + kt * 8 + 1);
      }
      if (layer > 0) {
#pragma unroll
        for (int kt = 0; kt < 16; ++kt) {
          fy[2 * kt] = aload(gy + kt * 8);
          fy[2 * kt + 1] = aload(gy + kt * 8 + 1);
        }
      }
      bool ok = true;
#pragma unroll
      for (int i = 0; i < 32; ++i)
        ok = ok && ((fh[i] >> 48) != 0x7F80ull) && ((fl[i] >> 48) != 0x7F80ull);
      if (layer > 0) {
#pragma unroll
        for (int i = 0; i < 32; ++i) ok = ok && ((fy[i] >> 48) != 0x7F80ull);
      }
      if (ok) break;
      __builtin_amdgcn_s_sleep(1);
    }

    f32x4 a0 = {b0, b1, b2, b3};
    f32x4 a1 = {0.f, 0.f, 0.f, 0.f}, a2 = a1, a3 = a1;
#pragma unroll
    for (int kt = 0; kt < 16; ++kt) {
      int kb = (kt * 64 + g4 * 16) ^ rxr;
      bf16x8 whv = *(const bf16x8*)(wb + rdoff + kb);
      bf16x8 wlv = *(const bf16x8*)(wb + 16384 + rdoff + kb);
      bf16x8 hv = __builtin_bit_cast(bf16x8, Q2{fh[2 * kt], fh[2 * kt + 1]});
      bf16x8 lv = __builtin_bit_cast(bf16x8, Q2{fl[2 * kt], fl[2 * kt + 1]});
      f32x4* ac = (kt & 3) == 0 ? &a0 : (kt & 3) == 1 ? &a1 : (kt & 3) == 2 ? &a2 : &a3;
      *ac = __builtin_amdgcn_mfma_f32_16x16x32_bf16(whv, hv, *ac, 0, 0, 0);
      *ac = __builtin_amdgcn_mfma_f32_16x16x32_bf16(wlv, hv, *ac, 0, 0, 0);
      *ac = __builtin_amdgcn_mfma_f32_16x16x32_bf16(whv, lv, *ac, 0, 0, 0);
      if (layer > 0) {
        bf16x8 wiv = *(const bf16x8*)(wb + 32768 + rdoff + kb);
        bf16x8 wjv = *(const bf16x8*)(wb + 49152 + rdoff + kb);
        bf16x8 yv = __builtin_bit_cast(bf16x8, Q2{fy[2 * kt], fy[2 * kt + 1]});
        int d = (kt + 2) & 3;
        f32x4* ad = d == 0 ? &a0 : d == 1 ? &a1 : d == 2 ? &a2 : &a3;
        *ad = __builtin_amdgcn_mfma_f32_16x16x32_bf16(wiv, yv, *ad, 0, 0, 0);
        *ad = __builtin_amdgcn_mfma_f32_16x16x32_bf16(wjv, yv, *ad, 0, 0, 0);
      }
    }
    if (layer == 0) {
#pragma unroll
      for (int kt = 0; kt < 4; ++kt) {
        int kb = (kt * 64 + g4 * 16) ^ rxr;
        bf16x8 wiv = *(const bf16x8*)(wb + 32768 + rdoff + kb);
        bf16x8 wjv = *(const bf16x8*)(wb + 49152 + rdoff + kb);
        bf16x8 xv = __builtin_bit_cast(bf16x8, fx[kt][0]);
        bf16x8 xq = __builtin_bit_cast(bf16x8, fx[kt][1]);
        a0 = __builtin_amdgcn_mfma_f32_16x16x32_bf16(wiv, xv, a0, 0, 0, 0);
        a1 = __builtin_amdgcn_mfma_f32_16x16x32_bf16(wjv, xv, a1, 0, 0, 0);
        a2 = __builtin_amdgcn_mfma_f32_16x16x32_bf16(wiv, xq, a2, 0, 0, 0);
      }
    }
    f32x4 s = (a0 + a1) + (a2 + a3);
    float v[4];
#pragma unroll
    for (int j = 0; j < 4; ++j) {
      float e = __expf(2.0f * s[j]);
      v[j] = 1.0f - 2.0f * __builtin_amdgcn_rcpf(e + 1.0f);
    }
    u64 hip = 0, lop = 0;
#pragma unroll
    for (int j = 0; j < 4; ++j) {
      u16 hh = f2bf(v[j]);
      u16 ll = f2bf(v[j] - bf2f(hh));
      hip |= (u64)hh << (16 * j);
      lop |= (u64)ll << (16 * j);
    }
    if (t < T_ - 1) {
      size_t so = ((size_t)((t + 1) & 15) * B_ + bb + r15) * (size_t)H_ + j0 + g4 * 4;
      astore((u64*)rhH + (so >> 2), hip);
      astore((u64*)rhL + (so >> 2), lop);
      size_t ss = ((size_t)((t + 9) & 15) * B_ + bb + r15) * (size_t)H_ + j0 + g4 * 4;
      astore((u64*)rhH + (ss >> 2), 0x7F807F807F807F80ull);
      astore((u64*)rhL + (ss >> 2), 0x7F807F807F807F80ull);
    }
    if (layer < 2) {
      size_t yo = ((size_t)t * B_ + bb + r15) * (size_t)H_ + j0 + g4 * 4;
      astore((u64*)yout + (yo >> 2), hip);
    }
    // flag release (relaxed, fired after data stores; canary net covers races)
    if (l == 0) astore(myflag, (u64)(t + 1));
    if (t == T_ - 1) {
      f32x4 hv4 = {v[0], v[1], v[2], v[3]};
      *(f32x4*)(hno + (size_t)(bb + r15) * H_ + j0 + g4 * 4) = hv4;
    }
  }
}

// ---------- final FC + sigmoid ----------
__global__ __launch_bounds__(64) void fc_kernel(const float* __restrict__ hn2,
                                                const float* __restrict__ wfc,
                                                const float* __restrict__ bfc,
                                                float* __restrict__ out) {
  int b = blockIdx.x, o = threadIdx.x;
  __shared__ float hs[H_];
  for (int i = o; i < H_; i += 64) hs[i] = hn2[(size_t)b * H_ + i];
  __syncthreads();
  float acc = bfc[o];
#pragma unroll 4
  for (int k = 0; k < H_; k += 4) {
    float4 wv = *(const float4*)(wfc + (size_t)o * H_ + k);
    acc += hs[k] * wv.x + hs[k + 1] * wv.y + hs[k + 2] * wv.z + hs[k + 3] * wv.w;
  }
  out[b * O_ + o] = 1.f / (1.f + expf(-acc));
}

extern "C" void kernel_launch(void* const* d_in, const int* in_sizes, int n_in,
                              void* d_out, int out_size, void* d_ws, size_t ws_size,
                              hipStream_t stream) {
  (void)in_sizes; (void)n_in; (void)out_size;
  const float* x = (const float*)d_in[0];
  const float* h0 = (const float*)d_in[1];
  const float* w_ih[3] = {(const float*)d_in[2], (const float*)d_in[6], (const float*)d_in[10]};
  const float* w_hh[3] = {(const float*)d_in[3], (const float*)d_in[7], (const float*)d_in[11]};
  const float* b_ih[3] = {(const float*)d_in[4], (const float*)d_in[8], (const float*)d_in[12]};
  const float* b_hh[3] = {(const float*)d_in[5], (const float*)d_in[9], (const float*)d_in[13]};
  const float* w_fc = (const float*)d_in[14];
  const float* b_fc = (const float*)d_in[15];
  float* out = (float*)d_out;
  float* hn = out + B_ * O_;

  char* p = (char*)d_ws;
  auto carve = [&](size_t bytes) {
    char* r = p;
    p += (bytes + 255) & ~(size_t)255;
    return r;
  };
  u16* y = (u16*)carve(2 * TBH * 2);                        // 128 MiB
  u16* xhi = (u16*)carve((size_t)T_ * B_ * I_ * 2);         // 16 MiB
  u16* xlo = (u16*)carve((size_t)T_ * B_ * I_ * 2);         // 16 MiB
  u16* hxh = (u16*)carve((size_t)3 * R16 * B_ * H_ * 2);    // 3 MiB
  u16* hxl = (u16*)carve((size_t)3 * R16 * B_ * H_ * 2);    // 3 MiB
  u16* whh_hi = (u16*)carve((size_t)3 * 262144 * 2);        // 1.5 MiB
  u16* whh_lo = (u16*)carve((size_t)3 * 262144 * 2);
  u16* wih_hi = (u16*)carve((size_t)3 * 262144 * 2);
  u16* wih_lo = (u16*)carve((size_t)3 * 262144 * 2);
  float* bsum = (float*)carve((size_t)3 * H_ * 4);
  u64* flags = (u64*)carve((size_t)3 * 4 * 32 * 8);
  size_t required = (size_t)(p - (char*)d_ws);
  if (required > ws_size) {
    int n = B_ * O_ + 3 * B_ * H_;
    sentinel_kernel<<<(n + 255) / 256, 256, 0, stream>>>(out, (float)(ws_size >> 20), n);
    return;
  }

  hipMemsetAsync(flags, 0, (size_t)3 * 4 * 32 * 8, stream);
  for (int l = 0; l < 3; ++l) {
    split_kernel<<<262144 / 256, 256, 0, stream>>>(w_hh[l], whh_hi + l * 262144,
                                                   whh_lo + l * 262144, 262144);
    int nih = (l == 0) ? H_ * I_ : H_ * H_;
    split_kernel<<<(nih + 255) / 256, 256, 0, stream>>>(w_ih[l], wih_hi + l * 262144,
                                                        wih_lo + l * 262144, nih);
    bsum_kernel<<<2, 256, 0, stream>>>(b_ih[l], b_hh[l], bsum + l * H_);
    h0ring_kernel<<<R16 * B_ * H_ / 256, 256, 0, stream>>>(
        h0 + (size_t)l * B_ * H_, hxh + (size_t)l * R16 * B_ * H_,
        hxl + (size_t)l * R16 * B_ * H_);
  }
  xsplit_kernel<<<T_ * B_ * I_ / 256, 256, 0, stream>>>(x, xhi, xlo);
  ycan_kernel<<<(unsigned)(TBH / 256), 256, 0, stream>>>((unsigned int*)y);

  rnn3_kernel<<<384, 64, 0, stream>>>(whh_hi, whh_lo, wih_hi, wih_lo, xhi, xlo,
                                      bsum, y, hxh, hxl, flags, hn);
  fc_kernel<<<B_, O_, 0, stream>>>(hn + 2 * (size_t)B_ * H_, w_fc, b_fc, out);
}